// Round 1
// baseline (66.229 us; speedup 1.0000x reference)
//
#include <hip/hip_runtime.h>

#define B_ 512
#define M_ 32
#define D_ 2048
#define K_ 3

// Pass 1: per-batch row sums + edge elements -> S_k -> 32x32 decay matvec -> coef[b,i,0..2]
__global__ __launch_bounds__(256) void ephaptic_rows(const float* __restrict__ x,
                                                     float* __restrict__ coef) {
    const int b = blockIdx.x;
    const int tid = threadIdx.x;
    const int wave = tid >> 6;
    const int lane = tid & 63;
    __shared__ float sT[M_], sF[M_], sL[M_];

    const float* xb = x + (size_t)b * M_ * D_;
    // each wave handles 8 rows (m), one at a time; 2048 floats = 512 float4 = 8/lane
    for (int mm = 0; mm < 8; ++mm) {
        const int m = wave * 8 + mm;
        const float4* row = (const float4*)(xb + (size_t)m * D_);
        float sum = 0.f, first = 0.f, last = 0.f;
#pragma unroll
        for (int q = 0; q < 8; ++q) {
            float4 v = row[lane + 64 * q];
            sum += (v.x + v.y) + (v.z + v.w);
            if (q == 0 && lane == 0) first = v.x;    // x[b][m][0]
            if (q == 7 && lane == 63) last = v.w;    // x[b][m][2047]
        }
#pragma unroll
        for (int off = 32; off > 0; off >>= 1)
            sum += __shfl_down(sum, off, 64);
        last = __shfl(last, 63, 64);
        if (lane == 0) { sT[m] = sum; sF[m] = first; sL[m] = last; }
    }
    __syncthreads();

    if (tid < M_) {
        const int i = tid;
        float r0 = 0.f, r1 = 0.f, r2 = 0.f;
        for (int j = 0; j < M_; ++j) {
            if (j == i) continue;
            const float dij = __expf(-0.5f * fabsf((float)(i - j)));
            const float T = sT[j];
            r0 += dij * (T - sL[j]);   // tap k=0 (offset -1): drop last element
            r1 += dij * T;             // tap k=1 (offset 0)
            r2 += dij * (T - sF[j]);   // tap k=2 (offset +1): drop first element
        }
        const float scale = 0.1f / (float)D_;
        float4 o;
        o.x = r0 * scale; o.y = r1 * scale; o.z = r2 * scale; o.w = 0.f;
        ((float4*)coef)[b * M_ + i] = o;
    }
}

// Pass 2: out[b,i,c] = x[b,i,c] + coef0*w[c,0] + coef1*w[c,1] + coef2*w[c,2]
__global__ __launch_bounds__(256) void ephaptic_out(const float* __restrict__ x,
                                                    const float* __restrict__ w,
                                                    const float* __restrict__ coef,
                                                    float* __restrict__ out) {
    const int row = blockIdx.x >> 1;            // b*M + i
    const int half = blockIdx.x & 1;
    const int c4 = half * 256 + threadIdx.x;    // float4 index within the D dim

    const float4 co = ((const float4*)coef)[row];
    const size_t base = (size_t)row * D_;
    const float4 xv = ((const float4*)(x + base))[c4];

    // w is [D,3] row-major; rows c0..c0+3 = 12 consecutive floats = 3 float4s
    const float4* wf = (const float4*)w;
    const float4 w0 = wf[c4 * 3 + 0];
    const float4 w1 = wf[c4 * 3 + 1];
    const float4 w2 = wf[c4 * 3 + 2];

    float4 o;
    o.x = xv.x + co.x * w0.x + co.y * w0.y + co.z * w0.z;
    o.y = xv.y + co.x * w0.w + co.y * w1.x + co.z * w1.y;
    o.z = xv.z + co.x * w1.z + co.y * w1.w + co.z * w2.x;
    o.w = xv.w + co.x * w2.y + co.y * w2.z + co.z * w2.w;
    ((float4*)(out + base))[c4] = o;
}

extern "C" void kernel_launch(void* const* d_in, const int* in_sizes, int n_in,
                              void* d_out, int out_size, void* d_ws, size_t ws_size,
                              hipStream_t stream) {
    const float* x = (const float*)d_in[0];
    const float* w = (const float*)d_in[1];
    float* out = (float*)d_out;
    float* coef = (float*)d_ws;   // B*M*4 floats = 256 KB

    ephaptic_rows<<<B_, 256, 0, stream>>>(x, coef);
    ephaptic_out<<<B_ * M_ * 2, 256, 0, stream>>>(x, w, coef, out);
}

// Round 2
// 55.710 us; speedup vs baseline: 1.1888x; 1.1888x over previous
//
#include <hip/hip_runtime.h>

#define B_ 512
#define M_ 32
#define D_ 2048

// One block per batch. 1024 threads = 32 rows x 32 threads/row.
// Each thread holds its 16 float4s of x in registers across the coef barrier,
// so x is fetched from HBM exactly once.
__global__ __launch_bounds__(1024) void ephaptic_fused(const float* __restrict__ x,
                                                       const float* __restrict__ w,
                                                       float* __restrict__ out) {
    const int b = blockIdx.x;
    const int tid = threadIdx.x;
    const int m = tid >> 5;   // row 0..31
    const int t = tid & 31;   // position group within row

    __shared__ float sT[M_], sF[M_], sL[M_];
    __shared__ float4 sC[M_];

    const size_t rowbase = ((size_t)b * M_ + m) * (size_t)D_;
    const float4* row = (const float4*)(x + rowbase);

    // Phase A: load row slice into registers, accumulate row sum.
    float4 v[16];
    float sum = 0.f;
#pragma unroll
    for (int q = 0; q < 16; ++q) {
        v[q] = row[t + 32 * q];
        sum += (v[q].x + v[q].y) + (v[q].z + v[q].w);
    }
    // butterfly within the 32-lane row group (xor offsets < 32 stay in-half)
#pragma unroll
    for (int off = 16; off > 0; off >>= 1)
        sum += __shfl_xor(sum, off, 64);
    if (t == 0)  { sT[m] = sum; sF[m] = v[0].x; }    // x[b][m][0]
    if (t == 31) { sL[m] = v[15].w; }                // x[b][m][2047]
    __syncthreads();

    // Phase B: 32x32 decay matvec -> per-row coefficients.
    if (tid < M_) {
        const int i = tid;
        float r0 = 0.f, r1 = 0.f, r2 = 0.f;
        for (int j = 0; j < M_; ++j) {
            if (j == i) continue;
            const float dij = __expf(-0.5f * fabsf((float)(i - j)));
            const float T = sT[j];
            r0 += dij * (T - sL[j]);   // tap k=0: drop last element
            r1 += dij * T;             // tap k=1
            r2 += dij * (T - sF[j]);   // tap k=2: drop first element
        }
        const float s = 0.1f / (float)D_;
        sC[i] = make_float4(r0 * s, r1 * s, r2 * s, 0.f);
    }
    __syncthreads();

    // Phase C: out = x + coef . w[c,:]  (w is [D,3] row-major; 12 floats = 3 float4 per c4)
    const float4 co = sC[m];  // LDS broadcast within row group
    const float4* wf = (const float4*)w;
    float4* orow = (float4*)(out + rowbase);
#pragma unroll
    for (int q = 0; q < 16; ++q) {
        const int c4 = t + 32 * q;
        const float4 w0 = wf[c4 * 3 + 0];
        const float4 w1 = wf[c4 * 3 + 1];
        const float4 w2 = wf[c4 * 3 + 2];
        float4 o;
        o.x = v[q].x + co.x * w0.x + co.y * w0.y + co.z * w0.z;
        o.y = v[q].y + co.x * w0.w + co.y * w1.x + co.z * w1.y;
        o.z = v[q].z + co.x * w1.z + co.y * w1.w + co.z * w2.x;
        o.w = v[q].w + co.x * w2.y + co.y * w2.z + co.z * w2.w;
        orow[c4] = o;
    }
}

extern "C" void kernel_launch(void* const* d_in, const int* in_sizes, int n_in,
                              void* d_out, int out_size, void* d_ws, size_t ws_size,
                              hipStream_t stream) {
    const float* x = (const float*)d_in[0];
    const float* w = (const float*)d_in[1];
    float* out = (float*)d_out;
    ephaptic_fused<<<B_, 1024, 0, stream>>>(x, w, out);
}